// Round 1
// baseline (267.089 us; speedup 1.0000x reference)
//
#include <hip/hip_runtime.h>
#include <stdint.h>

typedef __bf16 bf16_t;
typedef __bf16 bf16x8 __attribute__((ext_vector_type(8)));
typedef float f32x4 __attribute__((ext_vector_type(4)));

// async global->LDS, 16B per lane; LDS dest is wave-uniform base + lane*16
__device__ __forceinline__ void gload_lds16(const void* g, void* l) {
  __builtin_amdgcn_global_load_lds(
      (const __attribute__((address_space(1))) uint32_t*)g,
      (__attribute__((address_space(3))) uint32_t*)l, 16, 0, 0);
}

// ---------------- cast f32 -> bf16 (vectorized) ----------------
__global__ void cast_f32_bf16(const float* __restrict__ in,
                              bf16_t* __restrict__ out, int n4) {
  int i = blockIdx.x * blockDim.x + threadIdx.x;
  int stride = gridDim.x * blockDim.x;
  for (int idx = i; idx < n4; idx += stride) {
    float4 v = reinterpret_cast<const float4*>(in)[idx];
    union { bf16_t b[4]; uint2 u; } pk;
    pk.b[0] = (bf16_t)v.x; pk.b[1] = (bf16_t)v.y;
    pk.b[2] = (bf16_t)v.z; pk.b[3] = (bf16_t)v.w;
    reinterpret_cast<uint2*>(out)[idx] = pk.u;
  }
}

// ---------------- GEMM: C[M][N] = A[M][K] * B[N][K]^T (+bias) ----------------
// m97 structure: 128x128 tile, BK=32, 4 waves (2x2), each wave 64x64 via 4x4
// fragments of mfma_f32_16x16x32_bf16. global_load_lds width 16.
template <bool BF16_OUT>
__global__ __launch_bounds__(256)
void gemm_bt(const bf16_t* __restrict__ A,   // [M][K]
             const bf16_t* __restrict__ B,   // [N][K] (i.e. B^T of the math B)
             void* __restrict__ Cout,        // bf16 [M][N] or f32 [M][N]
             const float* __restrict__ bias, // len N (only if !BF16_OUT)
             int M, int N, int K) {
  __shared__ bf16_t Alds[128 * 32];
  __shared__ bf16_t Blds[128 * 32];
  const int tid = threadIdx.x;
  const int w = tid >> 6, l = tid & 63;
  const int wr = w >> 1, wc = w & 1;
  const int m0 = blockIdx.x * 128;
  const int n0 = blockIdx.y * 128;

  // staging geometry: each wave stages 2 chunks of 1KB per tile (A and B).
  // chunk ci covers LDS rows (w*2+ci)*16 .. +15 ; lane covers 16B:
  //   row = (w*2+ci)*16 + (l>>2), k elem = (l&3)*8
  const int srow = (w * 2) * 16 + (l >> 2);
  const int skel = (l & 3) * 8;
  const bf16_t* Ag0 = A + (size_t)(m0 + srow) * K + skel;
  const bf16_t* Bg0 = B + (size_t)(n0 + srow) * K + skel;

  f32x4 acc[4][4] = {};

  const int arow = wr * 64 + (l & 15);
  const int brow = wc * 64 + (l & 15);
  const int kslot = (l >> 4) * 8;  // consistent A/B k mapping

  for (int k0 = 0; k0 < K; k0 += 32) {
    gload_lds16(Ag0 + k0,                 &Alds[(w * 2 + 0) * 512]);
    gload_lds16(Ag0 + (size_t)16 * K + k0, &Alds[(w * 2 + 1) * 512]);
    gload_lds16(Bg0 + k0,                 &Blds[(w * 2 + 0) * 512]);
    gload_lds16(Bg0 + (size_t)16 * K + k0, &Blds[(w * 2 + 1) * 512]);
    __syncthreads();  // drains vmcnt(0) before barrier (compiler-enforced)

    bf16x8 av[4], bv[4];
#pragma unroll
    for (int i = 0; i < 4; ++i)
      av[i] = *reinterpret_cast<const bf16x8*>(&Alds[(arow + i * 16) * 32 + kslot]);
#pragma unroll
    for (int j = 0; j < 4; ++j)
      bv[j] = *reinterpret_cast<const bf16x8*>(&Blds[(brow + j * 16) * 32 + kslot]);
#pragma unroll
    for (int i = 0; i < 4; ++i)
#pragma unroll
      for (int j = 0; j < 4; ++j)
        acc[i][j] = __builtin_amdgcn_mfma_f32_16x16x32_bf16(av[i], bv[j], acc[i][j], 0, 0, 0);
    __syncthreads();
  }

  // epilogue: C/D layout col = lane&15, row = (lane>>4)*4 + reg
  const int rsub = (l >> 4) * 4;
  const int csub = l & 15;
  if (BF16_OUT) {
    bf16_t* C = (bf16_t*)Cout;
#pragma unroll
    for (int i = 0; i < 4; ++i)
#pragma unroll
      for (int j = 0; j < 4; ++j)
#pragma unroll
        for (int r = 0; r < 4; ++r) {
          int row = m0 + wr * 64 + i * 16 + rsub + r;
          int col = n0 + wc * 64 + j * 16 + csub;
          C[(size_t)row * N + col] = (bf16_t)acc[i][j][r];
        }
  } else {
    float* C = (float*)Cout;
#pragma unroll
    for (int i = 0; i < 4; ++i)
#pragma unroll
      for (int j = 0; j < 4; ++j)
#pragma unroll
        for (int r = 0; r < 4; ++r) {
          int row = m0 + wr * 64 + i * 16 + rsub + r;
          int col = n0 + wc * 64 + j * 16 + csub;
          C[(size_t)row * N + col] = acc[i][j][r] + bias[col];
        }
  }
}

// ---------------- per-token head-attention ----------------
// qkv row layout per token: head h -> f in [h*192, h*192+192):
//   q = f[h*192 .. +64), k = f[h*192+64 .. +128), v = f[h*192+128 .. +192)
// scores[h][g] = sum_d q[h][d]*k[g][d] / 8 ; softmax over g ; out[h][d] = sum_g p*v[g][d]
// One wave per token; 4 lanes per head (d-slices of 16).
__global__ __launch_bounds__(256)
void attn_heads(const bf16_t* __restrict__ qkv, bf16_t* __restrict__ out) {
  __shared__ float s[4][3072];
  const int w = threadIdx.x >> 6, l = threadIdx.x & 63;
  const size_t t = (size_t)blockIdx.x * 4 + w;
  const bf16_t* src = qkv + t * 3072;
#pragma unroll
  for (int i = 0; i < 6; ++i) {
    int f = (i * 64 + l) * 8;
    bf16x8 v = *reinterpret_cast<const bf16x8*>(&src[f]);
#pragma unroll
    for (int jj = 0; jj < 8; ++jj) s[w][f + jj] = (float)v[jj];
  }
  __syncthreads();

  const int h = l >> 2, ss = l & 3;
  float qr[16];
  const float* qb = &s[w][h * 192 + ss * 16];
#pragma unroll
  for (int d = 0; d < 16; ++d) qr[d] = qb[d];

  float sc[16];
#pragma unroll
  for (int g = 0; g < 16; ++g) {
    const float* kk = &s[w][g * 192 + 64 + ss * 16];
    float p = 0.f;
#pragma unroll
    for (int d = 0; d < 16; ++d) p += qr[d] * kk[d];
    p += __shfl_xor(p, 1);
    p += __shfl_xor(p, 2);
    sc[g] = p * 0.125f;  // /SCALE
  }
  float m = sc[0];
#pragma unroll
  for (int g = 1; g < 16; ++g) m = fmaxf(m, sc[g]);
  float sum = 0.f;
#pragma unroll
  for (int g = 0; g < 16; ++g) { sc[g] = __expf(sc[g] - m); sum += sc[g]; }
  float inv = 1.f / sum;

  float o[16] = {};
#pragma unroll
  for (int g = 0; g < 16; ++g) {
    float a = sc[g] * inv;
    const float* vv = &s[w][g * 192 + 128 + ss * 16];
#pragma unroll
    for (int d = 0; d < 16; ++d) o[d] += a * vv[d];
  }
  union { bf16_t b[16]; uint4 u[2]; } pk;
#pragma unroll
  for (int d = 0; d < 16; ++d) pk.b[d] = (bf16_t)o[d];
  uint4* dst = reinterpret_cast<uint4*>(out + t * 1024 + h * 64 + ss * 16);
  dst[0] = pk.u[0];
  dst[1] = pk.u[1];
}

// ---------------- launch ----------------
extern "C" void kernel_launch(void* const* d_in, const int* in_sizes, int n_in,
                              void* d_out, int out_size, void* d_ws, size_t ws_size,
                              hipStream_t stream) {
  const float* x     = (const float*)d_in[0];  // [8,2048,1024]
  const float* Wqkv  = (const float*)d_in[1];  // [3072,1024]
  const float* Wproj = (const float*)d_in[2];  // [1024,1024]
  const float* bproj = (const float*)d_in[3];  // [1024]
  float* out = (float*)d_out;

  const int M = 8 * 2048;   // 16384 tokens
  const int DM = 1024;      // d_model
  const int F = 3072;       // qkv features

  // workspace layout (~168 MB total)
  char* ws = (char*)d_ws;
  bf16_t* xb     = (bf16_t*)ws;  ws += (size_t)M * DM * 2;   // 33.6 MB
  bf16_t* wqkvb  = (bf16_t*)ws;  ws += (size_t)F * DM * 2;   //  6.3 MB
  bf16_t* wprojb = (bf16_t*)ws;  ws += (size_t)DM * DM * 2;  //  2.1 MB
  bf16_t* qkvb   = (bf16_t*)ws;  ws += (size_t)M * F * 2;    // 100.7 MB
  bf16_t* attnb  = (bf16_t*)ws;                               // 33.6 MB

  cast_f32_bf16<<<2048, 256, 0, stream>>>(x, xb, M * DM / 4);
  cast_f32_bf16<<<512, 256, 0, stream>>>(Wqkv, wqkvb, F * DM / 4);
  cast_f32_bf16<<<256, 256, 0, stream>>>(Wproj, wprojb, DM * DM / 4);

  gemm_bt<true><<<dim3(M / 128, F / 128), 256, 0, stream>>>(
      xb, wqkvb, (void*)qkvb, nullptr, M, F, DM);

  attn_heads<<<M / 4, 256, 0, stream>>>(qkvb, attnb);

  gemm_bt<false><<<dim3(M / 128, DM / 128), 256, 0, stream>>>(
      attnb, wprojb, (void*)out, bproj, M, DM, DM);
}